// Round 10
// baseline (246.293 us; speedup 1.0000x reference)
//
#include <hip/hip_runtime.h>

// DoubleSin via bf16 MFMA (16x16x32), zero-LDS, fused branches.
// Round-10: VALU reduction inside the fixed register wall (128 VGPR + 128
// AGPR/wave = file full at 2 waves/SIMD; occupancy and pipelining closed).
//  - fold 1/(2pi) into layer scales: activations use raw v_sin_f32
//    (revolutions) with NO input multiply. Carried value between layers is
//    g~ = g * r2pi; the 2pi factors cancel inside W' so the bf16 weight
//    fragments are UNCHANGED; only biases (*r2pi) and w4 (*2pi) rescale.
//    Activation: g~ = q~ + s^2 * r2pi  (s = v_sin(q~)).
//  - v_pk_fma_f32 / v_pk_mul_f32 (inline asm) for layer-1, the activation
//    polynomial, and layer-4 dot — halves full-rate VALU in those blocks.
// Structure otherwise round-9: one dispatch, blockIdx&1 selects branch,
// 2-term split (Wh*Bh + Wl*Bh), unsafeAtomicAdd into zeroed out.

typedef __attribute__((ext_vector_type(8))) short bf8v;
typedef __attribute__((ext_vector_type(4))) float f4v;
typedef __attribute__((ext_vector_type(2))) float f2v;

union BF8U { bf8v v; unsigned d[4]; unsigned short s[8]; };

#define R2PI  0.15915494309189535f
#define TWOPI 6.283185307179586f

__device__ __forceinline__ unsigned short f2bf(float f) {   // preamble only
    unsigned u = __builtin_bit_cast(unsigned, f);
    u += 0x7fffu + ((u >> 16) & 1u);
    return (unsigned short)(u >> 16);
}
__device__ __forceinline__ float bf2f(unsigned short b) {
    return __builtin_bit_cast(float, (unsigned)b << 16);
}
__device__ __forceinline__ unsigned cvt_pk_bf16(float lo, float hi) {
    unsigned r;
    asm("v_cvt_pk_bf16_f32 %0, %1, %2" : "=v"(r) : "v"(lo), "v"(hi));
    return r;
}
__device__ __forceinline__ float sin_rev(float x) {          // sin(2*pi*x)
    float r;
    asm("v_sin_f32 %0, %1" : "=v"(r) : "v"(x));
    return r;
}
__device__ __forceinline__ f2v pk_fma(f2v a, f2v b, f2v c) {
    f2v d;
    asm("v_pk_fma_f32 %0, %1, %2, %3" : "=v"(d) : "v"(a), "v"(b), "v"(c));
    return d;
}
__device__ __forceinline__ f2v pk_mul(f2v a, f2v b) {
    f2v d;
    asm("v_pk_mul_f32 %0, %1, %2" : "=v"(d) : "v"(a), "v"(b));
    return d;
}
__device__ __forceinline__ f4v pk_fma4(f4v a, f4v b, f4v c) {
    f2v a0 = {a[0], a[1]}, a1 = {a[2], a[3]};
    f2v b0 = {b[0], b[1]}, b1 = {b[2], b[3]};
    f2v c0 = {c[0], c[1]}, c1 = {c[2], c[3]};
    f2v d0 = pk_fma(a0, b0, c0), d1 = pk_fma(a1, b1, c1);
    f4v d = {d0[0], d0[1], d1[0], d1[1]};
    return d;
}

// q~ (revolutions) -> g~ = q~ + sin^2 * r2pi
__device__ __forceinline__ f4v act4(f4v q) {
    const float s0 = sin_rev(q[0]), s1 = sin_rev(q[1]);
    const float s2 = sin_rev(q[2]), s3 = sin_rev(q[3]);
    const f2v r2 = {R2PI, R2PI};
    f2v s01 = {s0, s1}, s23 = {s2, s3};
    f2v q01 = {q[0], q[1]}, q23 = {q[2], q[3]};
    f2v g01 = pk_fma(pk_mul(s01, s01), r2, q01);
    f2v g23 = pk_fma(pk_mul(s23, s23), r2, q23);
    f4v g = {g01[0], g01[1], g23[0], g23[1]};
    return g;
}

#define MFMA(a, b, c) __builtin_amdgcn_mfma_f32_16x16x32_bf16((a), (b), (c), 0, 0, 0)

// act on all 16 accs, then build bf16 B fragments
__device__ __forceinline__ void act_frags(f4v (&acc)[4], bf8v (&Bh)[2]) {
    #pragma unroll
    for (int t = 0; t < 4; ++t) acc[t] = act4(acc[t]);
    #pragma unroll
    for (int s2 = 0; s2 < 2; ++s2) {
        BF8U h;
        #pragma unroll
        for (int p = 0; p < 4; ++p) {
            const int t = 2 * s2 + (p >> 1);
            const int j0 = (p & 1) * 2;
            h.d[p] = cvt_pk_bf16(acc[t][j0], acc[t][j0 + 1]);
        }
        Bh[s2] = h.v;
    }
}

__global__ __launch_bounds__(256, 2) void mlp_fused(
    const float* __restrict__ x,
    const float* __restrict__ W1a, const float* __restrict__ b1a, const float* __restrict__ a1a,
    const float* __restrict__ W2a, const float* __restrict__ b2a, const float* __restrict__ a2a,
    const float* __restrict__ W3a, const float* __restrict__ b3a, const float* __restrict__ a3a,
    const float* __restrict__ W4a, const float* __restrict__ b4a,
    const float* __restrict__ W1b, const float* __restrict__ b1b, const float* __restrict__ a1b,
    const float* __restrict__ W2b, const float* __restrict__ b2b, const float* __restrict__ a2b,
    const float* __restrict__ W3b, const float* __restrict__ b3b, const float* __restrict__ a3b,
    const float* __restrict__ W4b, const float* __restrict__ b4b,
    float* __restrict__ out, int n)
{
    const int lane = threadIdx.x & 63;
    const int col  = lane & 15;
    const int g    = lane >> 4;
    const int br   = (int)(blockIdx.x & 1);
    const int sub  = (int)(blockIdx.x >> 1);
    const int wid  = sub * 4 + (int)(threadIdx.x >> 6);
    const int nwaves = (int)((gridDim.x >> 1) << 2);     // waves per branch
    const int ntiles = n >> 4;
    const float xscale = br ? 2.0f : 1.0f;

    const float* W1 = br ? W1b : W1a;  const float* b1 = br ? b1b : b1a;  const float* a1 = br ? a1b : a1a;
    const float* W2 = br ? W2b : W2a;  const float* b2 = br ? b2b : b2a;  const float* a2 = br ? a2b : a2a;
    const float* W3 = br ? W3b : W3a;  const float* b3 = br ? b3b : b3a;  const float* a3 = br ? a3b : a3a;
    const float* W4 = br ? W4b : W4a;  const float* b4 = br ? b4b : b4a;

    const bf8v z8 = {0, 0, 0, 0, 0, 0, 0, 0};

    // ---------------- preamble: fold params, build weight fragments --------
    // Layer 1 (VALU, revolutions): q~1 = (r2pi*xscale*a1*W1)*x + (r2pi*a1*b1)
    f4v w1p[4], b1p[4];
    #pragma unroll
    for (int t = 0; t < 4; ++t) {
        const int c0 = 16 * t + 4 * g;
        const f4v a1v = *(const f4v*)(a1 + c0);
        w1p[t] = (a1v * (xscale * R2PI)) * *(const f4v*)(W1 + c0);
        b1p[t] = (a1v * R2PI) * *(const f4v*)(b1 + c0);
    }

    // Layers 2,3 fragments: W'[o][k] = aout[o] * W[o][k] / ain[k]  (unchanged:
    // the 2pi of g~ -> g and the r2pi of q -> q~ cancel)
    bf8v W2h[4][2], W2l[4][2], W3h[4][2], W3l[4][2];
    #pragma unroll
    for (int L = 0; L < 2; ++L) {
        const float* W    = L ? W3 : W2;
        const float* aout = L ? a3 : a2;
        const float* ain  = L ? a2 : a1;
        #pragma unroll
        for (int s = 0; s < 2; ++s) {
            const int kb = 32 * s + 4 * g;
            const f4v aia = *(const f4v*)(ain + kb);
            const f4v aib = *(const f4v*)(ain + kb + 16);
            float ra[8];
            #pragma unroll
            for (int j = 0; j < 4; ++j) { ra[j] = 1.0f / aia[j]; ra[4 + j] = 1.0f / aib[j]; }
            #pragma unroll
            for (int t = 0; t < 4; ++t) {
                const int o = 16 * t + col;
                const f4v wa = *(const f4v*)(W + o * 64 + kb);
                const f4v wb = *(const f4v*)(W + o * 64 + kb + 16);
                const float ao = aout[o];
                bf8v hh = z8, ll = z8;
                #pragma unroll
                for (int j = 0; j < 8; ++j) {
                    const float wv = (j < 4) ? wa[j & 3] : wb[j & 3];
                    const float wp = ao * wv * ra[j];
                    unsigned short hb = f2bf(wp);
                    hh[j] = (short)hb;
                    ll[j] = (short)f2bf(wp - bf2f(hb));
                }
                if (L == 0) { W2h[t][s] = hh; W2l[t][s] = ll; }
                else        { W3h[t][s] = hh; W3l[t][s] = ll; }
            }
        }
    }

    // biases scaled to revolutions; w4'' = (W4/a3)*2pi
    f4v bias2[4], bias3[4], w4p[4];
    #pragma unroll
    for (int t = 0; t < 4; ++t) {
        const int c0 = 16 * t + 4 * g;
        bias2[t] = *(const f4v*)(b2 + c0) * *(const f4v*)(a2 + c0) * R2PI;
        bias3[t] = *(const f4v*)(b3 + c0) * *(const f4v*)(a3 + c0) * R2PI;
        w4p[t]   = *(const f4v*)(W4 + c0) / *(const f4v*)(a3 + c0) * TWOPI;
    }
    const float b4v = b4[0];

    // ---------------- main loop over 16-point tiles ------------------------
    int tile = wid;
    if (tile >= ntiles) return;
    float xc = x[tile * 16 + col];

    while (tile < ntiles) {
        const int tnext = tile + nwaves;
        float xn = 0.0f;
        if (tnext < ntiles) xn = x[tnext * 16 + col];

        // ---- layer 1 (packed fp32) ----
        f4v acc[4];
        const f4v xc4 = {xc, xc, xc, xc};
        #pragma unroll
        for (int t = 0; t < 4; ++t) acc[t] = pk_fma4(w1p[t], xc4, b1p[t]);
        bf8v Bh[2];
        act_frags(acc, Bh);            // g~1 -> fragments (bf16 RNE)

        // ---- layer 2 ----
        f4v acc2[4];
        #pragma unroll
        for (int t = 0; t < 4; ++t) {
            f4v d = bias2[t];
            #pragma unroll
            for (int s = 0; s < 2; ++s) {
                d = MFMA(W2h[t][s], Bh[s], d);
                d = MFMA(W2l[t][s], Bh[s], d);
            }
            acc2[t] = d;
        }
        act_frags(acc2, Bh);           // g~2 -> fragments

        // ---- layer 3 ----
        #pragma unroll
        for (int t = 0; t < 4; ++t) {
            f4v d = bias3[t];
            #pragma unroll
            for (int s = 0; s < 2; ++s) {
                d = MFMA(W3h[t][s], Bh[s], d);
                d = MFMA(W3l[t][s], Bh[s], d);
            }
            acc[t] = d;
        }
        #pragma unroll
        for (int t = 0; t < 4; ++t) acc[t] = act4(acc[t]);   // g~3 stays f32

        // ---- layer 4 (packed dot) ----
        f2v p2 = {0.0f, 0.0f};
        #pragma unroll
        for (int t = 0; t < 4; ++t) {
            f2v a0 = {acc[t][0], acc[t][1]}, a1v = {acc[t][2], acc[t][3]};
            f2v w0 = {w4p[t][0], w4p[t][1]}, w1v = {w4p[t][2], w4p[t][3]};
            p2 = pk_fma(w0, a0, p2);
            p2 = pk_fma(w1v, a1v, p2);
        }
        float p = p2[0] + p2[1];
        p += __shfl_xor(p, 16);
        p += __shfl_xor(p, 32);

        if (lane < 16) unsafeAtomicAdd(&out[tile * 16 + col], p + b4v);

        tile = tnext; xc = xn;
    }
}

extern "C" void kernel_launch(void* const* d_in, const int* in_sizes, int n_in,
                              void* d_out, int out_size, void* d_ws, size_t ws_size,
                              hipStream_t stream) {
    const float* x   = (const float*)d_in[0];
    const float* W1a = (const float*)d_in[1];
    const float* b1a = (const float*)d_in[2];
    const float* a1a = (const float*)d_in[3];
    const float* W2a = (const float*)d_in[4];
    const float* b2a = (const float*)d_in[5];
    const float* a2a = (const float*)d_in[6];
    const float* W3a = (const float*)d_in[7];
    const float* b3a = (const float*)d_in[8];
    const float* a3a = (const float*)d_in[9];
    const float* W4a = (const float*)d_in[10];
    const float* b4a = (const float*)d_in[11];
    const float* W1b = (const float*)d_in[12];
    const float* b1b = (const float*)d_in[13];
    const float* a1b = (const float*)d_in[14];
    const float* W2b = (const float*)d_in[15];
    const float* b2b = (const float*)d_in[16];
    const float* a2b = (const float*)d_in[17];
    const float* W3b = (const float*)d_in[18];
    const float* b3b = (const float*)d_in[19];
    const float* a3b = (const float*)d_in[20];
    const float* W4b = (const float*)d_in[21];
    const float* b4b = (const float*)d_in[22];

    const int n = in_sizes[0];
    float* out = (float*)d_out;

    hipMemsetAsync(out, 0, (size_t)n * sizeof(float), stream);
    mlp_fused<<<1024, 256, 0, stream>>>(x,
                                        W1a, b1a, a1a, W2a, b2a, a2a,
                                        W3a, b3a, a3a, W4a, b4a,
                                        W1b, b1b, a1b, W2b, b2b, a2b,
                                        W3b, b3b, a3b, W4b, b4b,
                                        out, n);
}

// Round 12
// 183.901 us; speedup vs baseline: 1.3393x; 1.3393x over previous
//
#include <hip/hip_runtime.h>

// DoubleSin via f16 MFMA (16x16x32), zero-LDS, fused branches.
// Round-12 = round-11 with compile fix: __builtin_amdgcn_cvt_pkrtz returns
// __fp16-vector; use __fp16 (not _Float16) for all fragment types.
//  - f16 mantissa (11b) vs bf16 (8b): one product term suffices ->
//    MFMA/tile 32 -> 16, weight AGPRs 128 -> 64.
//  - weights converted with (__fp16) cast (RNE, preamble only);
//    activations packed with __builtin_amdgcn_cvt_pkrtz (1 instr / 2 vals).
//  - round-10 lesson: NO hand-written v_pk_* asm (spilled); plain scalar
//    fma/sin code, compiler-scheduled.
// Structure: one dispatch, blockIdx&1 selects branch; D = W'.H with weights
// as A-operand; D registers of layer L are exactly the B fragment of layer
// L+1 (no cross-lane traffic). Snake scales folded into weights
// (W_L' = diag(a_L) W_L diag(1/a_{L-1}) -- fragments unchanged by the fold);
// activation g(q) = q + sin^2(q). unsafeAtomicAdd into zeroed out (exactly
// 2 adds/element, bitwise commutative -> deterministic).

typedef __fp16 h8v __attribute__((ext_vector_type(8)));
typedef __fp16 h2v __attribute__((ext_vector_type(2)));
typedef __attribute__((ext_vector_type(4))) float f4v;

union H8U { h8v v; h2v p[4]; };

#define MFMA16(a, b, c) __builtin_amdgcn_mfma_f32_16x16x32_f16((a), (b), (c), 0, 0, 0)

// g(q) = q + sin^2 q on all 16 accs, then build f16 B fragments (pkrtz)
__device__ __forceinline__ void act_frags(f4v (&acc)[4], h8v (&B)[2]) {
    #pragma unroll
    for (int t = 0; t < 4; ++t) {
        #pragma unroll
        for (int j = 0; j < 4; ++j) {
            float q = acc[t][j];
            float s = __sinf(q);
            acc[t][j] = fmaf(s, s, q);
        }
    }
    #pragma unroll
    for (int s2 = 0; s2 < 2; ++s2) {
        H8U u;
        u.p[0] = __builtin_amdgcn_cvt_pkrtz(acc[2 * s2][0],     acc[2 * s2][1]);
        u.p[1] = __builtin_amdgcn_cvt_pkrtz(acc[2 * s2][2],     acc[2 * s2][3]);
        u.p[2] = __builtin_amdgcn_cvt_pkrtz(acc[2 * s2 + 1][0], acc[2 * s2 + 1][1]);
        u.p[3] = __builtin_amdgcn_cvt_pkrtz(acc[2 * s2 + 1][2], acc[2 * s2 + 1][3]);
        B[s2] = u.v;
    }
}

__global__ __launch_bounds__(256, 2) void mlp_fused(
    const float* __restrict__ x,
    const float* __restrict__ W1a, const float* __restrict__ b1a, const float* __restrict__ a1a,
    const float* __restrict__ W2a, const float* __restrict__ b2a, const float* __restrict__ a2a,
    const float* __restrict__ W3a, const float* __restrict__ b3a, const float* __restrict__ a3a,
    const float* __restrict__ W4a, const float* __restrict__ b4a,
    const float* __restrict__ W1b, const float* __restrict__ b1b, const float* __restrict__ a1b,
    const float* __restrict__ W2b, const float* __restrict__ b2b, const float* __restrict__ a2b,
    const float* __restrict__ W3b, const float* __restrict__ b3b, const float* __restrict__ a3b,
    const float* __restrict__ W4b, const float* __restrict__ b4b,
    float* __restrict__ out, int n)
{
    const int lane = threadIdx.x & 63;
    const int col  = lane & 15;
    const int g    = lane >> 4;
    const int br   = (int)(blockIdx.x & 1);
    const int sub  = (int)(blockIdx.x >> 1);
    const int wid  = sub * 4 + (int)(threadIdx.x >> 6);
    const int nwaves = (int)((gridDim.x >> 1) << 2);     // waves per branch
    const int ntiles = n >> 4;
    const float xscale = br ? 2.0f : 1.0f;

    const float* W1 = br ? W1b : W1a;  const float* b1 = br ? b1b : b1a;  const float* a1 = br ? a1b : a1a;
    const float* W2 = br ? W2b : W2a;  const float* b2 = br ? b2b : b2a;  const float* a2 = br ? a2b : a2a;
    const float* W3 = br ? W3b : W3a;  const float* b3 = br ? b3b : b3a;  const float* a3 = br ? a3b : a3a;
    const float* W4 = br ? W4b : W4a;  const float* b4 = br ? b4b : b4a;

    // ---------------- preamble: fold params, build weight fragments --------
    // Layer 1 (VALU): q1[ch] = (a1*W1*xscale)[ch] * x + (a1*b1)[ch]
    f4v w1p[4], b1p[4];
    #pragma unroll
    for (int t = 0; t < 4; ++t) {
        const int c0 = 16 * t + 4 * g;
        const f4v a1v = *(const f4v*)(a1 + c0);
        w1p[t] = (a1v * xscale) * *(const f4v*)(W1 + c0);
        b1p[t] = a1v * *(const f4v*)(b1 + c0);
    }

    // Layers 2,3 fragments (f16 RNE): W'[o][k] = aout[o] * W[o][k] / ain[k]
    h8v W2f[4][2], W3f[4][2];
    #pragma unroll
    for (int L = 0; L < 2; ++L) {
        const float* W    = L ? W3 : W2;
        const float* aout = L ? a3 : a2;
        const float* ain  = L ? a2 : a1;
        #pragma unroll
        for (int s = 0; s < 2; ++s) {
            const int kb = 32 * s + 4 * g;
            const f4v aia = *(const f4v*)(ain + kb);
            const f4v aib = *(const f4v*)(ain + kb + 16);
            float ra[8];
            #pragma unroll
            for (int j = 0; j < 4; ++j) { ra[j] = 1.0f / aia[j]; ra[4 + j] = 1.0f / aib[j]; }
            #pragma unroll
            for (int t = 0; t < 4; ++t) {
                const int o = 16 * t + col;
                const f4v wa = *(const f4v*)(W + o * 64 + kb);
                const f4v wb = *(const f4v*)(W + o * 64 + kb + 16);
                const float ao = aout[o];
                h8v hh;
                #pragma unroll
                for (int j = 0; j < 8; ++j) {
                    const float wv = (j < 4) ? wa[j & 3] : wb[j & 3];
                    hh[j] = (__fp16)(ao * wv * ra[j]);
                }
                if (L == 0) W2f[t][s] = hh;
                else        W3f[t][s] = hh;
            }
        }
    }

    // scaled biases and w4' = w4 / a3 (per-lane quad = 16t + 4g + j)
    f4v bias2[4], bias3[4], w4p[4];
    #pragma unroll
    for (int t = 0; t < 4; ++t) {
        const int c0 = 16 * t + 4 * g;
        bias2[t] = *(const f4v*)(b2 + c0) * *(const f4v*)(a2 + c0);
        bias3[t] = *(const f4v*)(b3 + c0) * *(const f4v*)(a3 + c0);
        w4p[t]   = *(const f4v*)(W4 + c0) / *(const f4v*)(a3 + c0);
    }
    const float b4v = b4[0];

    // ---------------- main loop over 16-point tiles ------------------------
    int tile = wid;
    if (tile >= ntiles) return;
    float xc = x[tile * 16 + col];

    while (tile < ntiles) {
        const int tnext = tile + nwaves;
        float xn = 0.0f;
        if (tnext < ntiles) xn = x[tnext * 16 + col];

        // ---- layer 1 (fp32 VALU) ----
        f4v acc[4];
        #pragma unroll
        for (int t = 0; t < 4; ++t) {
            #pragma unroll
            for (int j = 0; j < 4; ++j) acc[t][j] = fmaf(w1p[t][j], xc, b1p[t][j]);
        }
        h8v B[2];
        act_frags(acc, B);             // g1 -> f16 fragments

        // ---- layer 2 ----
        f4v acc2[4];
        #pragma unroll
        for (int t = 0; t < 4; ++t) {
            f4v d = bias2[t];
            #pragma unroll
            for (int s = 0; s < 2; ++s) d = MFMA16(W2f[t][s], B[s], d);
            acc2[t] = d;
        }
        act_frags(acc2, B);            // g2 -> f16 fragments

        // ---- layer 3 ----
        #pragma unroll
        for (int t = 0; t < 4; ++t) {
            f4v d = bias3[t];
            #pragma unroll
            for (int s = 0; s < 2; ++s) d = MFMA16(W3f[t][s], B[s], d);
            acc[t] = d;
        }
        #pragma unroll
        for (int t = 0; t < 4; ++t) {
            #pragma unroll
            for (int j = 0; j < 4; ++j) {
                float q = acc[t][j];
                float s = __sinf(q);
                acc[t][j] = fmaf(s, s, q);
            }
        }

        // ---- layer 4 ----
        float p = 0.0f;
        #pragma unroll
        for (int t = 0; t < 4; ++t) {
            #pragma unroll
            for (int j = 0; j < 4; ++j) p = fmaf(w4p[t][j], acc[t][j], p);
        }
        p += __shfl_xor(p, 16);
        p += __shfl_xor(p, 32);

        if (lane < 16) unsafeAtomicAdd(&out[tile * 16 + col], p + b4v);

        tile = tnext; xc = xn;
    }
}

extern "C" void kernel_launch(void* const* d_in, const int* in_sizes, int n_in,
                              void* d_out, int out_size, void* d_ws, size_t ws_size,
                              hipStream_t stream) {
    const float* x   = (const float*)d_in[0];
    const float* W1a = (const float*)d_in[1];
    const float* b1a = (const float*)d_in[2];
    const float* a1a = (const float*)d_in[3];
    const float* W2a = (const float*)d_in[4];
    const float* b2a = (const float*)d_in[5];
    const float* a2a = (const float*)d_in[6];
    const float* W3a = (const float*)d_in[7];
    const float* b3a = (const float*)d_in[8];
    const float* a3a = (const float*)d_in[9];
    const float* W4a = (const float*)d_in[10];
    const float* b4a = (const float*)d_in[11];
    const float* W1b = (const float*)d_in[12];
    const float* b1b = (const float*)d_in[13];
    const float* a1b = (const float*)d_in[14];
    const float* W2b = (const float*)d_in[15];
    const float* b2b = (const float*)d_in[16];
    const float* a2b = (const float*)d_in[17];
    const float* W3b = (const float*)d_in[18];
    const float* b3b = (const float*)d_in[19];
    const float* a3b = (const float*)d_in[20];
    const float* W4b = (const float*)d_in[21];
    const float* b4b = (const float*)d_in[22];

    const int n = in_sizes[0];
    float* out = (float*)d_out;

    (void)hipMemsetAsync(out, 0, (size_t)n * sizeof(float), stream);
    mlp_fused<<<1024, 256, 0, stream>>>(x,
                                        W1a, b1a, a1a, W2a, b2a, a2a,
                                        W3a, b3a, a3a, W4a, b4a,
                                        W1b, b1b, a1b, W2b, b2b, a2b,
                                        W3b, b3b, a3b, W4b, b4b,
                                        out, n);
}

// Round 13
// 164.219 us; speedup vs baseline: 1.4998x; 1.1199x over previous
//
#include <hip/hip_runtime.h>

// DoubleSin via f16 MFMA (16x16x32), zero-LDS, fused branches.
// Round-13 = round-12 + ILP x2 (32-point super-tile / wave).
// Why now: f16 single-term halved both weight regs (64) and MFMA count, so
// static state (80 param + 64 weight) + 2x dynamic (~50) ~= 244 <= 256-reg
// budget at 2 waves/SIMD. Round-7's bf16 3-term attempt needed ~270 and
// spilled; this fits. Two independent per-tile dependency chains fill the
// ~35% idle issue slots seen at VALUBusy=65%.
// Tripwire: FETCH ~8 MB / WRITE ~16 MB must NOT balloon (spill signature).
// Structure: one dispatch, blockIdx&1 selects branch; D = W'.H with weights
// as A-operand; D registers of layer L are exactly the B fragment of layer
// L+1. Snake scales folded into weights; activation g(q) = q + sin^2(q).
// unsafeAtomicAdd into zeroed out (2 adds/element, deterministic).

typedef __fp16 h8v __attribute__((ext_vector_type(8)));
typedef __fp16 h2v __attribute__((ext_vector_type(2)));
typedef __attribute__((ext_vector_type(4))) float f4v;

union H8U { h8v v; h2v p[4]; };

#define MFMA16(a, b, c) __builtin_amdgcn_mfma_f32_16x16x32_f16((a), (b), (c), 0, 0, 0)

// g(q) = q + sin^2 q on all 16 accs, then build f16 B fragments (pkrtz)
__device__ __forceinline__ void act_frags(f4v (&acc)[4], h8v (&B)[2]) {
    #pragma unroll
    for (int t = 0; t < 4; ++t) {
        #pragma unroll
        for (int j = 0; j < 4; ++j) {
            float q = acc[t][j];
            float s = __sinf(q);
            acc[t][j] = fmaf(s, s, q);
        }
    }
    #pragma unroll
    for (int s2 = 0; s2 < 2; ++s2) {
        H8U u;
        u.p[0] = __builtin_amdgcn_cvt_pkrtz(acc[2 * s2][0],     acc[2 * s2][1]);
        u.p[1] = __builtin_amdgcn_cvt_pkrtz(acc[2 * s2][2],     acc[2 * s2][3]);
        u.p[2] = __builtin_amdgcn_cvt_pkrtz(acc[2 * s2 + 1][0], acc[2 * s2 + 1][1]);
        u.p[3] = __builtin_amdgcn_cvt_pkrtz(acc[2 * s2 + 1][2], acc[2 * s2 + 1][3]);
        B[s2] = u.v;
    }
}

__global__ __launch_bounds__(256, 2) void mlp_fused(
    const float* __restrict__ x,
    const float* __restrict__ W1a, const float* __restrict__ b1a, const float* __restrict__ a1a,
    const float* __restrict__ W2a, const float* __restrict__ b2a, const float* __restrict__ a2a,
    const float* __restrict__ W3a, const float* __restrict__ b3a, const float* __restrict__ a3a,
    const float* __restrict__ W4a, const float* __restrict__ b4a,
    const float* __restrict__ W1b, const float* __restrict__ b1b, const float* __restrict__ a1b,
    const float* __restrict__ W2b, const float* __restrict__ b2b, const float* __restrict__ a2b,
    const float* __restrict__ W3b, const float* __restrict__ b3b, const float* __restrict__ a3b,
    const float* __restrict__ W4b, const float* __restrict__ b4b,
    float* __restrict__ out, int n)
{
    const int lane = threadIdx.x & 63;
    const int col  = lane & 15;
    const int g    = lane >> 4;
    const int br   = (int)(blockIdx.x & 1);
    const int sub  = (int)(blockIdx.x >> 1);
    const int wid  = sub * 4 + (int)(threadIdx.x >> 6);
    const int nwaves = (int)((gridDim.x >> 1) << 2);     // waves per branch
    const int nst = n >> 5;                              // 32-point super-tiles
    const float xscale = br ? 2.0f : 1.0f;

    const float* W1 = br ? W1b : W1a;  const float* b1 = br ? b1b : b1a;  const float* a1 = br ? a1b : a1a;
    const float* W2 = br ? W2b : W2a;  const float* b2 = br ? b2b : b2a;  const float* a2 = br ? a2b : a2a;
    const float* W3 = br ? W3b : W3a;  const float* b3 = br ? b3b : b3a;  const float* a3 = br ? a3b : a3a;
    const float* W4 = br ? W4b : W4a;  const float* b4 = br ? b4b : b4a;

    // ---------------- preamble: fold params, build weight fragments --------
    // Layer 1 (VALU): q1[ch] = (a1*W1*xscale)[ch] * x + (a1*b1)[ch]
    f4v w1p[4], b1p[4];
    #pragma unroll
    for (int t = 0; t < 4; ++t) {
        const int c0 = 16 * t + 4 * g;
        const f4v a1v = *(const f4v*)(a1 + c0);
        w1p[t] = (a1v * xscale) * *(const f4v*)(W1 + c0);
        b1p[t] = a1v * *(const f4v*)(b1 + c0);
    }

    // Layers 2,3 fragments (f16 RNE): W'[o][k] = aout[o] * W[o][k] / ain[k]
    h8v W2f[4][2], W3f[4][2];
    #pragma unroll
    for (int L = 0; L < 2; ++L) {
        const float* W    = L ? W3 : W2;
        const float* aout = L ? a3 : a2;
        const float* ain  = L ? a2 : a1;
        #pragma unroll
        for (int s = 0; s < 2; ++s) {
            const int kb = 32 * s + 4 * g;
            const f4v aia = *(const f4v*)(ain + kb);
            const f4v aib = *(const f4v*)(ain + kb + 16);
            float ra[8];
            #pragma unroll
            for (int j = 0; j < 4; ++j) { ra[j] = 1.0f / aia[j]; ra[4 + j] = 1.0f / aib[j]; }
            #pragma unroll
            for (int t = 0; t < 4; ++t) {
                const int o = 16 * t + col;
                const f4v wa = *(const f4v*)(W + o * 64 + kb);
                const f4v wb = *(const f4v*)(W + o * 64 + kb + 16);
                const float ao = aout[o];
                h8v hh;
                #pragma unroll
                for (int j = 0; j < 8; ++j) {
                    const float wv = (j < 4) ? wa[j & 3] : wb[j & 3];
                    hh[j] = (__fp16)(ao * wv * ra[j]);
                }
                if (L == 0) W2f[t][s] = hh;
                else        W3f[t][s] = hh;
            }
        }
    }

    // scaled biases and w4' = w4 / a3 (per-lane quad = 16t + 4g + j)
    f4v bias2[4], bias3[4], w4p[4];
    #pragma unroll
    for (int t = 0; t < 4; ++t) {
        const int c0 = 16 * t + 4 * g;
        bias2[t] = *(const f4v*)(b2 + c0) * *(const f4v*)(a2 + c0);
        bias3[t] = *(const f4v*)(b3 + c0) * *(const f4v*)(a3 + c0);
        w4p[t]   = *(const f4v*)(W4 + c0) / *(const f4v*)(a3 + c0);
    }
    const float b4v = b4[0];

    // ---------------- main loop over 32-point super-tiles ------------------
    int st = wid;
    if (st >= nst) return;
    float xA = x[st * 32 + col];
    float xB = x[st * 32 + 16 + col];

    while (st < nst) {
        const int snext = st + nwaves;
        float xAn = 0.0f, xBn = 0.0f;
        if (snext < nst) {
            xAn = x[snext * 32 + col];
            xBn = x[snext * 32 + 16 + col];
        }

        // ---- layer 1 (fp32 VALU), both tiles ----
        f4v accA[4], accB[4];
        #pragma unroll
        for (int t = 0; t < 4; ++t) {
            #pragma unroll
            for (int j = 0; j < 4; ++j) {
                accA[t][j] = fmaf(w1p[t][j], xA, b1p[t][j]);
                accB[t][j] = fmaf(w1p[t][j], xB, b1p[t][j]);
            }
        }
        h8v BA[2], BB[2];
        act_frags(accA, BA);
        act_frags(accB, BB);

        // ---- layer 2, both tiles ----
        f4v acc2A[4], acc2B[4];
        #pragma unroll
        for (int t = 0; t < 4; ++t) {
            f4v dA = bias2[t], dB = bias2[t];
            #pragma unroll
            for (int s = 0; s < 2; ++s) {
                dA = MFMA16(W2f[t][s], BA[s], dA);
                dB = MFMA16(W2f[t][s], BB[s], dB);
            }
            acc2A[t] = dA; acc2B[t] = dB;
        }
        act_frags(acc2A, BA);
        act_frags(acc2B, BB);

        // ---- layer 3, both tiles ----
        #pragma unroll
        for (int t = 0; t < 4; ++t) {
            f4v dA = bias3[t], dB = bias3[t];
            #pragma unroll
            for (int s = 0; s < 2; ++s) {
                dA = MFMA16(W3f[t][s], BA[s], dA);
                dB = MFMA16(W3f[t][s], BB[s], dB);
            }
            accA[t] = dA; accB[t] = dB;
        }
        #pragma unroll
        for (int t = 0; t < 4; ++t) {
            #pragma unroll
            for (int j = 0; j < 4; ++j) {
                float qA = accA[t][j], qB = accB[t][j];
                float sA = __sinf(qA), sB = __sinf(qB);
                accA[t][j] = fmaf(sA, sA, qA);
                accB[t][j] = fmaf(sB, sB, qB);
            }
        }

        // ---- layer 4, both tiles ----
        float pA = 0.0f, pB = 0.0f;
        #pragma unroll
        for (int t = 0; t < 4; ++t) {
            #pragma unroll
            for (int j = 0; j < 4; ++j) {
                pA = fmaf(w4p[t][j], accA[t][j], pA);
                pB = fmaf(w4p[t][j], accB[t][j], pB);
            }
        }
        pA += __shfl_xor(pA, 16); pA += __shfl_xor(pA, 32);
        pB += __shfl_xor(pB, 16); pB += __shfl_xor(pB, 32);

        const float pW = (lane < 16) ? pA : pB;
        if (lane < 32) unsafeAtomicAdd(&out[st * 32 + (lane & 31)], pW + b4v);

        st = snext; xA = xAn; xB = xBn;
    }
}

extern "C" void kernel_launch(void* const* d_in, const int* in_sizes, int n_in,
                              void* d_out, int out_size, void* d_ws, size_t ws_size,
                              hipStream_t stream) {
    const float* x   = (const float*)d_in[0];
    const float* W1a = (const float*)d_in[1];
    const float* b1a = (const float*)d_in[2];
    const float* a1a = (const float*)d_in[3];
    const float* W2a = (const float*)d_in[4];
    const float* b2a = (const float*)d_in[5];
    const float* a2a = (const float*)d_in[6];
    const float* W3a = (const float*)d_in[7];
    const float* b3a = (const float*)d_in[8];
    const float* a3a = (const float*)d_in[9];
    const float* W4a = (const float*)d_in[10];
    const float* b4a = (const float*)d_in[11];
    const float* W1b = (const float*)d_in[12];
    const float* b1b = (const float*)d_in[13];
    const float* a1b = (const float*)d_in[14];
    const float* W2b = (const float*)d_in[15];
    const float* b2b = (const float*)d_in[16];
    const float* a2b = (const float*)d_in[17];
    const float* W3b = (const float*)d_in[18];
    const float* b3b = (const float*)d_in[19];
    const float* a3b = (const float*)d_in[20];
    const float* W4b = (const float*)d_in[21];
    const float* b4b = (const float*)d_in[22];

    const int n = in_sizes[0];
    float* out = (float*)d_out;

    (void)hipMemsetAsync(out, 0, (size_t)n * sizeof(float), stream);
    mlp_fused<<<1024, 256, 0, stream>>>(x,
                                        W1a, b1a, a1a, W2a, b2a, a2a,
                                        W3a, b3a, a3a, W4a, b4a,
                                        W1b, b1b, a1b, W2b, b2b, a2b,
                                        W3b, b3b, a3b, W4b, b4b,
                                        out, n);
}

// Round 14
// 157.032 us; speedup vs baseline: 1.5684x; 1.0458x over previous
//
#include <hip/hip_runtime.h>

// DoubleSin via f16 MFMA (16x16x32), zero-LDS, fused branches.
// Round-14 = round-13 with ILP x4 (64-point super-tile / wave).
// Empirical register model from r12->r13: per-tile dynamic cost is only ~28
// VGPR (compiler reuses acc/acc2 within a chain), so 4 chains ~= 44 static
// + 112 dynamic + 64 AGPR ~= 220 <= 256 budget at 2 waves/SIMD -> no spills.
// 4 independent dependency chains fill the 29% idle issue slots (VALUBusy 71%).
// All 64 lanes store now: lane l -> tile l>>4, col l&15.
// Tripwire: FETCH must stay ~8.4 MB (ballooning = spill signature -> revert).
// Structure: one dispatch, blockIdx&1 selects branch; D = W'.H with weights
// as A-operand; D registers of layer L are exactly the B fragment of layer
// L+1. Snake scales folded into weights; activation g(q) = q + sin^2(q).
// unsafeAtomicAdd into zeroed out (2 adds/element, deterministic).

typedef __fp16 h8v __attribute__((ext_vector_type(8)));
typedef __fp16 h2v __attribute__((ext_vector_type(2)));
typedef __attribute__((ext_vector_type(4))) float f4v;

union H8U { h8v v; h2v p[4]; };

#define MFMA16(a, b, c) __builtin_amdgcn_mfma_f32_16x16x32_f16((a), (b), (c), 0, 0, 0)

// g(q) = q + sin^2 q on all 16 accs, then build f16 B fragments (pkrtz)
__device__ __forceinline__ void act_frags(f4v (&acc)[4], h8v (&B)[2]) {
    #pragma unroll
    for (int t = 0; t < 4; ++t) {
        #pragma unroll
        for (int j = 0; j < 4; ++j) {
            float q = acc[t][j];
            float s = __sinf(q);
            acc[t][j] = fmaf(s, s, q);
        }
    }
    #pragma unroll
    for (int s2 = 0; s2 < 2; ++s2) {
        H8U u;
        u.p[0] = __builtin_amdgcn_cvt_pkrtz(acc[2 * s2][0],     acc[2 * s2][1]);
        u.p[1] = __builtin_amdgcn_cvt_pkrtz(acc[2 * s2][2],     acc[2 * s2][3]);
        u.p[2] = __builtin_amdgcn_cvt_pkrtz(acc[2 * s2 + 1][0], acc[2 * s2 + 1][1]);
        u.p[3] = __builtin_amdgcn_cvt_pkrtz(acc[2 * s2 + 1][2], acc[2 * s2 + 1][3]);
        B[s2] = u.v;
    }
}

__global__ __launch_bounds__(256, 2) void mlp_fused(
    const float* __restrict__ x,
    const float* __restrict__ W1a, const float* __restrict__ b1a, const float* __restrict__ a1a,
    const float* __restrict__ W2a, const float* __restrict__ b2a, const float* __restrict__ a2a,
    const float* __restrict__ W3a, const float* __restrict__ b3a, const float* __restrict__ a3a,
    const float* __restrict__ W4a, const float* __restrict__ b4a,
    const float* __restrict__ W1b, const float* __restrict__ b1b, const float* __restrict__ a1b,
    const float* __restrict__ W2b, const float* __restrict__ b2b, const float* __restrict__ a2b,
    const float* __restrict__ W3b, const float* __restrict__ b3b, const float* __restrict__ a3b,
    const float* __restrict__ W4b, const float* __restrict__ b4b,
    float* __restrict__ out, int n)
{
    const int lane = threadIdx.x & 63;
    const int col  = lane & 15;
    const int g    = lane >> 4;
    const int br   = (int)(blockIdx.x & 1);
    const int sub  = (int)(blockIdx.x >> 1);
    const int wid  = sub * 4 + (int)(threadIdx.x >> 6);
    const int nwaves = (int)((gridDim.x >> 1) << 2);     // waves per branch
    const int nst = n >> 6;                              // 64-point super-tiles
    const float xscale = br ? 2.0f : 1.0f;

    const float* W1 = br ? W1b : W1a;  const float* b1 = br ? b1b : b1a;  const float* a1 = br ? a1b : a1a;
    const float* W2 = br ? W2b : W2a;  const float* b2 = br ? b2b : b2a;  const float* a2 = br ? a2b : a2a;
    const float* W3 = br ? W3b : W3a;  const float* b3 = br ? b3b : b3a;  const float* a3 = br ? a3b : a3a;
    const float* W4 = br ? W4b : W4a;  const float* b4 = br ? b4b : b4a;

    // ---------------- preamble: fold params, build weight fragments --------
    // Layer 1 (VALU): q1[ch] = (a1*W1*xscale)[ch] * x + (a1*b1)[ch]
    f4v w1p[4], b1p[4];
    #pragma unroll
    for (int t = 0; t < 4; ++t) {
        const int c0 = 16 * t + 4 * g;
        const f4v a1v = *(const f4v*)(a1 + c0);
        w1p[t] = (a1v * xscale) * *(const f4v*)(W1 + c0);
        b1p[t] = a1v * *(const f4v*)(b1 + c0);
    }

    // Layers 2,3 fragments (f16 RNE): W'[o][k] = aout[o] * W[o][k] / ain[k]
    h8v W2f[4][2], W3f[4][2];
    #pragma unroll
    for (int L = 0; L < 2; ++L) {
        const float* W    = L ? W3 : W2;
        const float* aout = L ? a3 : a2;
        const float* ain  = L ? a2 : a1;
        #pragma unroll
        for (int s = 0; s < 2; ++s) {
            const int kb = 32 * s + 4 * g;
            const f4v aia = *(const f4v*)(ain + kb);
            const f4v aib = *(const f4v*)(ain + kb + 16);
            float ra[8];
            #pragma unroll
            for (int j = 0; j < 4; ++j) { ra[j] = 1.0f / aia[j]; ra[4 + j] = 1.0f / aib[j]; }
            #pragma unroll
            for (int t = 0; t < 4; ++t) {
                const int o = 16 * t + col;
                const f4v wa = *(const f4v*)(W + o * 64 + kb);
                const f4v wb = *(const f4v*)(W + o * 64 + kb + 16);
                const float ao = aout[o];
                h8v hh;
                #pragma unroll
                for (int j = 0; j < 8; ++j) {
                    const float wv = (j < 4) ? wa[j & 3] : wb[j & 3];
                    hh[j] = (__fp16)(ao * wv * ra[j]);
                }
                if (L == 0) W2f[t][s] = hh;
                else        W3f[t][s] = hh;
            }
        }
    }

    // scaled biases and w4' = w4 / a3 (per-lane quad = 16t + 4g + j)
    f4v bias2[4], bias3[4], w4p[4];
    #pragma unroll
    for (int t = 0; t < 4; ++t) {
        const int c0 = 16 * t + 4 * g;
        bias2[t] = *(const f4v*)(b2 + c0) * *(const f4v*)(a2 + c0);
        bias3[t] = *(const f4v*)(b3 + c0) * *(const f4v*)(a3 + c0);
        w4p[t]   = *(const f4v*)(W4 + c0) / *(const f4v*)(a3 + c0);
    }
    const float b4v = b4[0];

    // ---------------- main loop over 64-point super-tiles ------------------
    int st = wid;
    if (st >= nst) return;
    float xA = x[st * 64 + col];
    float xB = x[st * 64 + 16 + col];
    float xC = x[st * 64 + 32 + col];
    float xD = x[st * 64 + 48 + col];

    while (st < nst) {
        const int snext = st + nwaves;
        float xAn = 0.0f, xBn = 0.0f, xCn = 0.0f, xDn = 0.0f;
        if (snext < nst) {
            xAn = x[snext * 64 + col];
            xBn = x[snext * 64 + 16 + col];
            xCn = x[snext * 64 + 32 + col];
            xDn = x[snext * 64 + 48 + col];
        }

        // ---- layer 1 (fp32 VALU), 4 tiles ----
        f4v accA[4], accB[4], accC[4], accD[4];
        #pragma unroll
        for (int t = 0; t < 4; ++t) {
            #pragma unroll
            for (int j = 0; j < 4; ++j) {
                accA[t][j] = fmaf(w1p[t][j], xA, b1p[t][j]);
                accB[t][j] = fmaf(w1p[t][j], xB, b1p[t][j]);
                accC[t][j] = fmaf(w1p[t][j], xC, b1p[t][j]);
                accD[t][j] = fmaf(w1p[t][j], xD, b1p[t][j]);
            }
        }
        h8v BA[2], BB[2], BC[2], BD[2];
        act_frags(accA, BA);
        act_frags(accB, BB);
        act_frags(accC, BC);
        act_frags(accD, BD);

        // ---- layer 2, 4 tiles ----
        #pragma unroll
        for (int t = 0; t < 4; ++t) {
            f4v dA = bias2[t], dB = bias2[t], dC = bias2[t], dD = bias2[t];
            #pragma unroll
            for (int s = 0; s < 2; ++s) {
                dA = MFMA16(W2f[t][s], BA[s], dA);
                dB = MFMA16(W2f[t][s], BB[s], dB);
                dC = MFMA16(W2f[t][s], BC[s], dC);
                dD = MFMA16(W2f[t][s], BD[s], dD);
            }
            accA[t] = dA; accB[t] = dB; accC[t] = dC; accD[t] = dD;
        }
        act_frags(accA, BA);
        act_frags(accB, BB);
        act_frags(accC, BC);
        act_frags(accD, BD);

        // ---- layer 3, 4 tiles ----
        #pragma unroll
        for (int t = 0; t < 4; ++t) {
            f4v dA = bias3[t], dB = bias3[t], dC = bias3[t], dD = bias3[t];
            #pragma unroll
            for (int s = 0; s < 2; ++s) {
                dA = MFMA16(W3f[t][s], BA[s], dA);
                dB = MFMA16(W3f[t][s], BB[s], dB);
                dC = MFMA16(W3f[t][s], BC[s], dC);
                dD = MFMA16(W3f[t][s], BD[s], dD);
            }
            accA[t] = dA; accB[t] = dB; accC[t] = dC; accD[t] = dD;
        }
        #pragma unroll
        for (int t = 0; t < 4; ++t) {
            #pragma unroll
            for (int j = 0; j < 4; ++j) {
                float qA = accA[t][j], qB = accB[t][j];
                float qC = accC[t][j], qD = accD[t][j];
                float sA = __sinf(qA), sB = __sinf(qB);
                float sC = __sinf(qC), sD = __sinf(qD);
                accA[t][j] = fmaf(sA, sA, qA);
                accB[t][j] = fmaf(sB, sB, qB);
                accC[t][j] = fmaf(sC, sC, qC);
                accD[t][j] = fmaf(sD, sD, qD);
            }
        }

        // ---- layer 4, 4 tiles ----
        float pA = 0.0f, pB = 0.0f, pC = 0.0f, pD = 0.0f;
        #pragma unroll
        for (int t = 0; t < 4; ++t) {
            #pragma unroll
            for (int j = 0; j < 4; ++j) {
                pA = fmaf(w4p[t][j], accA[t][j], pA);
                pB = fmaf(w4p[t][j], accB[t][j], pB);
                pC = fmaf(w4p[t][j], accC[t][j], pC);
                pD = fmaf(w4p[t][j], accD[t][j], pD);
            }
        }
        pA += __shfl_xor(pA, 16); pA += __shfl_xor(pA, 32);
        pB += __shfl_xor(pB, 16); pB += __shfl_xor(pB, 32);
        pC += __shfl_xor(pC, 16); pC += __shfl_xor(pC, 32);
        pD += __shfl_xor(pD, 16); pD += __shfl_xor(pD, 32);

        float pW = pA;
        if (g == 1) pW = pB;
        if (g == 2) pW = pC;
        if (g == 3) pW = pD;
        unsafeAtomicAdd(&out[st * 64 + lane], pW + b4v);

        st = snext; xA = xAn; xB = xBn; xC = xCn; xD = xDn;
    }
}

extern "C" void kernel_launch(void* const* d_in, const int* in_sizes, int n_in,
                              void* d_out, int out_size, void* d_ws, size_t ws_size,
                              hipStream_t stream) {
    const float* x   = (const float*)d_in[0];
    const float* W1a = (const float*)d_in[1];
    const float* b1a = (const float*)d_in[2];
    const float* a1a = (const float*)d_in[3];
    const float* W2a = (const float*)d_in[4];
    const float* b2a = (const float*)d_in[5];
    const float* a2a = (const float*)d_in[6];
    const float* W3a = (const float*)d_in[7];
    const float* b3a = (const float*)d_in[8];
    const float* a3a = (const float*)d_in[9];
    const float* W4a = (const float*)d_in[10];
    const float* b4a = (const float*)d_in[11];
    const float* W1b = (const float*)d_in[12];
    const float* b1b = (const float*)d_in[13];
    const float* a1b = (const float*)d_in[14];
    const float* W2b = (const float*)d_in[15];
    const float* b2b = (const float*)d_in[16];
    const float* a2b = (const float*)d_in[17];
    const float* W3b = (const float*)d_in[18];
    const float* b3b = (const float*)d_in[19];
    const float* a3b = (const float*)d_in[20];
    const float* W4b = (const float*)d_in[21];
    const float* b4b = (const float*)d_in[22];

    const int n = in_sizes[0];
    float* out = (float*)d_out;

    (void)hipMemsetAsync(out, 0, (size_t)n * sizeof(float), stream);
    mlp_fused<<<1024, 256, 0, stream>>>(x,
                                        W1a, b1a, a1a, W2a, b2a, a2a,
                                        W3a, b3a, a3a, W4a, b4a,
                                        W1b, b1b, a1b, W2b, b2b, a2b,
                                        W3b, b3b, a3b, W4b, b4b,
                                        out, n);
}

// Round 15
// 151.557 us; speedup vs baseline: 1.6251x; 1.0361x over previous
//
#include <hip/hip_runtime.h>

// DoubleSin via f16 MFMA (16x16x32), zero-LDS, fused branches.
// Round-15 = round-14 + native v_sin_f32 via the revolutions fold.
// Counter audit: VALU-busy ~2350 cyc/tile vs ~640 source-level -> __sinf is
// expanding to a ~18-instr range-reduced polynomial (48 calls/tile = the
// missing ~1700 cyc). Fix: carry g~ = r2pi*g between layers so activations
// use raw v_sin_f32 (input in revolutions, here <= ~5 rev):
//   s = v_sin(q~); g~ = fmaf(s*s, r2pi, q~)   -- 3 instrs, r2pi is a free
//   inline constant (0.159154943).
// Fold algebra (verified round 10): W2'/W3' fragments UNCHANGED (2pi/r2pi
// cancel); biases *= r2pi; w4' *= 2pi; layer-1 w/b *= r2pi.
// Round-10's regression was the v_pk_* asm (spills) -- NOT this fold; no pk
// asm here. ILP x4 structure of round 14 kept verbatim.
// Tripwires: absmax > 0.0199 (v_sin accuracy) or FETCH ballooning -> revert.

typedef __fp16 h8v __attribute__((ext_vector_type(8)));
typedef __fp16 h2v __attribute__((ext_vector_type(2)));
typedef __attribute__((ext_vector_type(4))) float f4v;

union H8U { h8v v; h2v p[4]; };

#define R2PI  0.15915494309189535f
#define TWOPI 6.283185307179586f

__device__ __forceinline__ float sin_rev(float x) {   // sin(2*pi*x)
    float r;
    asm("v_sin_f32 %0, %1" : "=v"(r) : "v"(x));
    return r;
}

#define MFMA16(a, b, c) __builtin_amdgcn_mfma_f32_16x16x32_f16((a), (b), (c), 0, 0, 0)

// g~(q~) = q~ + sin_rev(q~)^2 * r2pi on all 16 accs, then f16 B fragments
__device__ __forceinline__ void act_frags(f4v (&acc)[4], h8v (&B)[2]) {
    #pragma unroll
    for (int t = 0; t < 4; ++t) {
        #pragma unroll
        for (int j = 0; j < 4; ++j) {
            float q = acc[t][j];
            float s = sin_rev(q);
            acc[t][j] = fmaf(s * s, R2PI, q);
        }
    }
    #pragma unroll
    for (int s2 = 0; s2 < 2; ++s2) {
        H8U u;
        u.p[0] = __builtin_amdgcn_cvt_pkrtz(acc[2 * s2][0],     acc[2 * s2][1]);
        u.p[1] = __builtin_amdgcn_cvt_pkrtz(acc[2 * s2][2],     acc[2 * s2][3]);
        u.p[2] = __builtin_amdgcn_cvt_pkrtz(acc[2 * s2 + 1][0], acc[2 * s2 + 1][1]);
        u.p[3] = __builtin_amdgcn_cvt_pkrtz(acc[2 * s2 + 1][2], acc[2 * s2 + 1][3]);
        B[s2] = u.v;
    }
}

__global__ __launch_bounds__(256, 2) void mlp_fused(
    const float* __restrict__ x,
    const float* __restrict__ W1a, const float* __restrict__ b1a, const float* __restrict__ a1a,
    const float* __restrict__ W2a, const float* __restrict__ b2a, const float* __restrict__ a2a,
    const float* __restrict__ W3a, const float* __restrict__ b3a, const float* __restrict__ a3a,
    const float* __restrict__ W4a, const float* __restrict__ b4a,
    const float* __restrict__ W1b, const float* __restrict__ b1b, const float* __restrict__ a1b,
    const float* __restrict__ W2b, const float* __restrict__ b2b, const float* __restrict__ a2b,
    const float* __restrict__ W3b, const float* __restrict__ b3b, const float* __restrict__ a3b,
    const float* __restrict__ W4b, const float* __restrict__ b4b,
    float* __restrict__ out, int n)
{
    const int lane = threadIdx.x & 63;
    const int col  = lane & 15;
    const int g    = lane >> 4;
    const int br   = (int)(blockIdx.x & 1);
    const int sub  = (int)(blockIdx.x >> 1);
    const int wid  = sub * 4 + (int)(threadIdx.x >> 6);
    const int nwaves = (int)((gridDim.x >> 1) << 2);     // waves per branch
    const int nst = n >> 6;                              // 64-point super-tiles
    const float xscale = br ? 2.0f : 1.0f;

    const float* W1 = br ? W1b : W1a;  const float* b1 = br ? b1b : b1a;  const float* a1 = br ? a1b : a1a;
    const float* W2 = br ? W2b : W2a;  const float* b2 = br ? b2b : b2a;  const float* a2 = br ? a2b : a2a;
    const float* W3 = br ? W3b : W3a;  const float* b3 = br ? b3b : b3a;  const float* a3 = br ? a3b : a3a;
    const float* W4 = br ? W4b : W4a;  const float* b4 = br ? b4b : b4a;

    // ---------------- preamble: fold params, build weight fragments --------
    // Layer 1 (VALU, revolutions): q~1 = (r2pi*xscale*a1*W1)*x + (r2pi*a1*b1)
    f4v w1p[4], b1p[4];
    #pragma unroll
    for (int t = 0; t < 4; ++t) {
        const int c0 = 16 * t + 4 * g;
        const f4v a1v = *(const f4v*)(a1 + c0);
        w1p[t] = (a1v * (xscale * R2PI)) * *(const f4v*)(W1 + c0);
        b1p[t] = (a1v * R2PI) * *(const f4v*)(b1 + c0);
    }

    // Layers 2,3 fragments (f16 RNE): W'[o][k] = aout[o] * W[o][k] / ain[k]
    // (unchanged by the revolutions fold: 2pi/r2pi cancel)
    h8v W2f[4][2], W3f[4][2];
    #pragma unroll
    for (int L = 0; L < 2; ++L) {
        const float* W    = L ? W3 : W2;
        const float* aout = L ? a3 : a2;
        const float* ain  = L ? a2 : a1;
        #pragma unroll
        for (int s = 0; s < 2; ++s) {
            const int kb = 32 * s + 4 * g;
            const f4v aia = *(const f4v*)(ain + kb);
            const f4v aib = *(const f4v*)(ain + kb + 16);
            float ra[8];
            #pragma unroll
            for (int j = 0; j < 4; ++j) { ra[j] = 1.0f / aia[j]; ra[4 + j] = 1.0f / aib[j]; }
            #pragma unroll
            for (int t = 0; t < 4; ++t) {
                const int o = 16 * t + col;
                const f4v wa = *(const f4v*)(W + o * 64 + kb);
                const f4v wb = *(const f4v*)(W + o * 64 + kb + 16);
                const float ao = aout[o];
                h8v hh;
                #pragma unroll
                for (int j = 0; j < 8; ++j) {
                    const float wv = (j < 4) ? wa[j & 3] : wb[j & 3];
                    hh[j] = (__fp16)(ao * wv * ra[j]);
                }
                if (L == 0) W2f[t][s] = hh;
                else        W3f[t][s] = hh;
            }
        }
    }

    // biases scaled to revolutions; w4'' = (W4/a3)*2pi
    f4v bias2[4], bias3[4], w4p[4];
    #pragma unroll
    for (int t = 0; t < 4; ++t) {
        const int c0 = 16 * t + 4 * g;
        bias2[t] = *(const f4v*)(b2 + c0) * *(const f4v*)(a2 + c0) * R2PI;
        bias3[t] = *(const f4v*)(b3 + c0) * *(const f4v*)(a3 + c0) * R2PI;
        w4p[t]   = *(const f4v*)(W4 + c0) / *(const f4v*)(a3 + c0) * TWOPI;
    }
    const float b4v = b4[0];

    // ---------------- main loop over 64-point super-tiles ------------------
    int st = wid;
    if (st >= nst) return;
    float xA = x[st * 64 + col];
    float xB = x[st * 64 + 16 + col];
    float xC = x[st * 64 + 32 + col];
    float xD = x[st * 64 + 48 + col];

    while (st < nst) {
        const int snext = st + nwaves;
        float xAn = 0.0f, xBn = 0.0f, xCn = 0.0f, xDn = 0.0f;
        if (snext < nst) {
            xAn = x[snext * 64 + col];
            xBn = x[snext * 64 + 16 + col];
            xCn = x[snext * 64 + 32 + col];
            xDn = x[snext * 64 + 48 + col];
        }

        // ---- layer 1 (fp32 VALU), 4 tiles ----
        f4v accA[4], accB[4], accC[4], accD[4];
        #pragma unroll
        for (int t = 0; t < 4; ++t) {
            #pragma unroll
            for (int j = 0; j < 4; ++j) {
                accA[t][j] = fmaf(w1p[t][j], xA, b1p[t][j]);
                accB[t][j] = fmaf(w1p[t][j], xB, b1p[t][j]);
                accC[t][j] = fmaf(w1p[t][j], xC, b1p[t][j]);
                accD[t][j] = fmaf(w1p[t][j], xD, b1p[t][j]);
            }
        }
        h8v BA[2], BB[2], BC[2], BD[2];
        act_frags(accA, BA);
        act_frags(accB, BB);
        act_frags(accC, BC);
        act_frags(accD, BD);

        // ---- layer 2, 4 tiles ----
        #pragma unroll
        for (int t = 0; t < 4; ++t) {
            f4v dA = bias2[t], dB = bias2[t], dC = bias2[t], dD = bias2[t];
            #pragma unroll
            for (int s = 0; s < 2; ++s) {
                dA = MFMA16(W2f[t][s], BA[s], dA);
                dB = MFMA16(W2f[t][s], BB[s], dB);
                dC = MFMA16(W2f[t][s], BC[s], dC);
                dD = MFMA16(W2f[t][s], BD[s], dD);
            }
            accA[t] = dA; accB[t] = dB; accC[t] = dC; accD[t] = dD;
        }
        act_frags(accA, BA);
        act_frags(accB, BB);
        act_frags(accC, BC);
        act_frags(accD, BD);

        // ---- layer 3, 4 tiles ----
        #pragma unroll
        for (int t = 0; t < 4; ++t) {
            f4v dA = bias3[t], dB = bias3[t], dC = bias3[t], dD = bias3[t];
            #pragma unroll
            for (int s = 0; s < 2; ++s) {
                dA = MFMA16(W3f[t][s], BA[s], dA);
                dB = MFMA16(W3f[t][s], BB[s], dB);
                dC = MFMA16(W3f[t][s], BC[s], dC);
                dD = MFMA16(W3f[t][s], BD[s], dD);
            }
            accA[t] = dA; accB[t] = dB; accC[t] = dC; accD[t] = dD;
        }
        #pragma unroll
        for (int t = 0; t < 4; ++t) {
            #pragma unroll
            for (int j = 0; j < 4; ++j) {
                float qA = accA[t][j], qB = accB[t][j];
                float qC = accC[t][j], qD = accD[t][j];
                float sA = sin_rev(qA), sB = sin_rev(qB);
                float sC = sin_rev(qC), sD = sin_rev(qD);
                accA[t][j] = fmaf(sA * sA, R2PI, qA);
                accB[t][j] = fmaf(sB * sB, R2PI, qB);
                accC[t][j] = fmaf(sC * sC, R2PI, qC);
                accD[t][j] = fmaf(sD * sD, R2PI, qD);
            }
        }

        // ---- layer 4, 4 tiles ----
        float pA = 0.0f, pB = 0.0f, pC = 0.0f, pD = 0.0f;
        #pragma unroll
        for (int t = 0; t < 4; ++t) {
            #pragma unroll
            for (int j = 0; j < 4; ++j) {
                pA = fmaf(w4p[t][j], accA[t][j], pA);
                pB = fmaf(w4p[t][j], accB[t][j], pB);
                pC = fmaf(w4p[t][j], accC[t][j], pC);
                pD = fmaf(w4p[t][j], accD[t][j], pD);
            }
        }
        pA += __shfl_xor(pA, 16); pA += __shfl_xor(pA, 32);
        pB += __shfl_xor(pB, 16); pB += __shfl_xor(pB, 32);
        pC += __shfl_xor(pC, 16); pC += __shfl_xor(pC, 32);
        pD += __shfl_xor(pD, 16); pD += __shfl_xor(pD, 32);

        float pW = pA;
        if (g == 1) pW = pB;
        if (g == 2) pW = pC;
        if (g == 3) pW = pD;
        unsafeAtomicAdd(&out[st * 64 + lane], pW + b4v);

        st = snext; xA = xAn; xB = xBn; xC = xCn; xD = xDn;
    }
}

extern "C" void kernel_launch(void* const* d_in, const int* in_sizes, int n_in,
                              void* d_out, int out_size, void* d_ws, size_t ws_size,
                              hipStream_t stream) {
    const float* x   = (const float*)d_in[0];
    const float* W1a = (const float*)d_in[1];
    const float* b1a = (const float*)d_in[2];
    const float* a1a = (const float*)d_in[3];
    const float* W2a = (const float*)d_in[4];
    const float* b2a = (const float*)d_in[5];
    const float* a2a = (const float*)d_in[6];
    const float* W3a = (const float*)d_in[7];
    const float* b3a = (const float*)d_in[8];
    const float* a3a = (const float*)d_in[9];
    const float* W4a = (const float*)d_in[10];
    const float* b4a = (const float*)d_in[11];
    const float* W1b = (const float*)d_in[12];
    const float* b1b = (const float*)d_in[13];
    const float* a1b = (const float*)d_in[14];
    const float* W2b = (const float*)d_in[15];
    const float* b2b = (const float*)d_in[16];
    const float* a2b = (const float*)d_in[17];
    const float* W3b = (const float*)d_in[18];
    const float* b3b = (const float*)d_in[19];
    const float* a3b = (const float*)d_in[20];
    const float* W4b = (const float*)d_in[21];
    const float* b4b = (const float*)d_in[22];

    const int n = in_sizes[0];
    float* out = (float*)d_out;

    (void)hipMemsetAsync(out, 0, (size_t)n * sizeof(float), stream);
    mlp_fused<<<1024, 256, 0, stream>>>(x,
                                        W1a, b1a, a1a, W2a, b2a, a2a,
                                        W3a, b3a, a3a, W4a, b4a,
                                        W1b, b1b, a1b, W2b, b2b, a2b,
                                        W3b, b3b, a3b, W4b, b4b,
                                        out, n);
}